// Round 6
// baseline (545.844 us; speedup 1.0000x reference)
//
#include <hip/hip_runtime.h>
#include <math.h>

#define DDIM 16
#define NSTEPS 64

typedef __fp16   fp16x2  __attribute__((ext_vector_type(2)));
typedef _Float16 h2      __attribute__((ext_vector_type(2)));
typedef _Float16 half4   __attribute__((ext_vector_type(4)));
typedef float    floatx4 __attribute__((ext_vector_type(4)));

union pk_u      { fp16x2 fv; h2 hv; unsigned u; };
union h2x2_h4   { h2 g2[2]; half4 h4; };
union pk2_to_h4 { fp16x2 p2[2]; half4 h4; };
union us_h      { unsigned short u; _Float16 h; };

// ---------------------------------------------------------------------------
// Pre-pack W^T / V^T into per-lane MFMA A-operand fragments (f16).
// V fragments are pre-scaled by 1/NSTEPS.
// ---------------------------------------------------------------------------
__global__ __launch_bounds__(256) void pack_wv(const float* __restrict__ W,
                                               const float* __restrict__ V,
                                               half4* __restrict__ pw,
                                               half4* __restrict__ pv)
{
    int t = blockIdx.x * 256 + threadIdx.x;   // 0..4095 = 64 steps * 64 lanes
    int L = t & 63;
    int s = t >> 6;
    int q = L >> 4, r = L & 15;
    const float inv_n = 1.0f / (float)NSTEPS;
    const float* Ws = W + s * DDIM * DDIM;
    const float* Vs = V + s * DDIM * DDIM;
    half4 w, v;
    #pragma unroll
    for (int j = 0; j < 4; ++j) {
        w[j] = (_Float16)Ws[(4 * q + j) * DDIM + r];
        v[j] = (_Float16)(Vs[(4 * q + j) * DDIM + r] * inv_n);
    }
    pw[t] = w;
    pv[t] = v;
}

// ---------------------------------------------------------------------------
// SIGN-FOLDED GELU LUT: indexed by the top 9 bits of |x|'s f16 pattern
// (5 exp + 4 mantissa) -> 512 log-spaced segments over the positive f16
// domain.  Entry i: packed f16 (a,b), gelu(x) ~= a*x + b for x>0 on the
// segment.  For x<0 we use gelu(x) = gelu(|x|) - |x|  =>  slope (1-a),
// same b.  Folding makes +v / -v hit the SAME LDS address (broadcast, free)
// instead of same-bank-different-address (guaranteed 2-way conflict).
// ---------------------------------------------------------------------------
__global__ __launch_bounds__(256) void build_lut_abs(unsigned* __restrict__ lut)
{
    int i = blockIdx.x * 256 + threadIdx.x;   // 0..511
    int eo = i >> 4;
    int en = (i + 1) >> 4;
    float a, b;
    if (eo >= 31 || en >= 31) {               // segment touches inf/nan codes
        a = 1.0f; b = 0.0f;                   // g = x exact for huge |x|
    } else {
        us_h c0, c1;
        c0.u = (unsigned short)(i << 6);
        c1.u = (unsigned short)((i + 1) << 6);
        float x0 = (float)c0.h, x1 = (float)c1.h;
        float g0 = 0.5f * x0 * (1.0f + erff(x0 * 0.70710678f));
        float g1 = 0.5f * x1 * (1.0f + erff(x1 * 0.70710678f));
        a = (g1 - g0) / (x1 - x0);
        b = g0 - a * x0;
    }
    us_h ah, bh;
    ah.h = (_Float16)a;
    bh.h = (_Float16)b;
    lut[i] = ((unsigned)bh.u << 16) | (unsigned)ah.u;
}

// ---------------------------------------------------------------------------
// Main kernel (R4 structure, sign-folded LUT). GELU per element pair:
//   uabs = U & 0x7FFF7FFF ; 2x ds_read_b32 gather from 2KB table
//   A,B via 2x v_perm ; sm = f16 1.0 per negative half (shift/and/mul24)
//   Aeff = sm*(1-2A) + A ; g = U*Aeff + B   (all v_pk_fma_f16, exact-fma
//   path: no catastrophic cancellation on the negative branch)
// ---------------------------------------------------------------------------
__global__ __launch_bounds__(256) void resnet_mfma_kernel(
    const float* __restrict__ x,
    const half4* __restrict__ pw,
    const half4* __restrict__ pv,
    const unsigned* __restrict__ lut_g,
    float* __restrict__ out)
{
    __shared__ unsigned lutw[512];   // 2 KB

    const int tid  = threadIdx.x;
    const int lane = tid & 63;
    const int wave = tid >> 6;
    const int q = lane >> 4, r = lane & 15;

    // Stage LUT into LDS: 128 uint4 = 512 u32.
    if (tid < 128) {
        const uint4* src = reinterpret_cast<const uint4*>(lut_g);
        reinterpret_cast<uint4*>(lutw)[tid] = src[tid];
    }

    const long rowbase = (long)blockIdx.x * 256 + (long)wave * 64;

    floatx4 h[4];
    #pragma unroll
    for (int t = 0; t < 4; ++t) {
        const float4* p = reinterpret_cast<const float4*>(
            x + (rowbase + t * 16 + r) * DDIM + 4 * q);
        float4 v = *p;
        h[t][0] = v.x; h[t][1] = v.y; h[t][2] = v.z; h[t][3] = v.w;
    }

    half4 wf = pw[lane];
    half4 vf = pv[lane];

    __syncthreads();   // LUT ready

    const char* lb = reinterpret_cast<const char*>(lutw);
    const h2 one = {(_Float16)1.0f, (_Float16)1.0f};

    for (int s = 0; s < NSTEPS; ++s) {
        int sn = (s + 1) & (NSTEPS - 1);          // last iter wraps to 0 (unused)
        half4 wfn = pw[sn * 64 + lane];
        half4 vfn = pv[sn * 64 + lane];

        #pragma unroll
        for (int t = 0; t < 4; ++t) {
            pk2_to_h4 hc;
            hc.p2[0] = __builtin_amdgcn_cvt_pkrtz(h[t][0], h[t][1]);
            hc.p2[1] = __builtin_amdgcn_cvt_pkrtz(h[t][2], h[t][3]);

            floatx4 zero = {0.f, 0.f, 0.f, 0.f};
            floatx4 u = __builtin_amdgcn_mfma_f32_16x16x16f16(wf, hc.h4, zero, 0, 0, 0);

            // u -> packed f16 (also the PWL input)
            pk_u p01, p23;
            p01.fv = __builtin_amdgcn_cvt_pkrtz(u[0], u[1]);
            p23.fv = __builtin_amdgcn_cvt_pkrtz(u[2], u[3]);

            // magnitude-indexed byte offsets: entry = |bits| >> 6, addr = 4*entry
            unsigned ua01 = p01.u & 0x7FFF7FFFu;
            unsigned ua23 = p23.u & 0x7FFF7FFFu;
            unsigned off0 = (ua01 >> 4) & 0x7FCu;
            unsigned off1 = (ua01 >> 20) & 0x7FCu;
            unsigned off2 = (ua23 >> 4) & 0x7FCu;
            unsigned off3 = (ua23 >> 20) & 0x7FCu;

            unsigned e0 = *reinterpret_cast<const unsigned*>(lb + off0);
            unsigned e1 = *reinterpret_cast<const unsigned*>(lb + off1);
            unsigned e2 = *reinterpret_cast<const unsigned*>(lb + off2);
            unsigned e3 = *reinterpret_cast<const unsigned*>(lb + off3);

            // repack (b|a)(b|a) -> A=(a1|a0), B=(b1|b0)
            pk_u A01, B01, A23, B23, SM01, SM23;
            A01.u = __builtin_amdgcn_perm(e1, e0, 0x05040100u);
            B01.u = __builtin_amdgcn_perm(e1, e0, 0x07060302u);
            A23.u = __builtin_amdgcn_perm(e3, e2, 0x05040100u);
            B23.u = __builtin_amdgcn_perm(e3, e2, 0x07060302u);

            // per-half sign mask as f16 1.0 (negative) / 0.0 (positive)
            SM01.u = ((p01.u >> 15) & 0x00010001u) * 0x3C00u;
            SM23.u = ((p23.u >> 15) & 0x00010001u) * 0x3C00u;

            // Aeff = a + sm*(1-2a)  ->  a (x>0) or 1-a (x<0); g = u*Aeff + b
            h2 T01 = one - A01.hv - A01.hv;
            h2 T23 = one - A23.hv - A23.hv;
            h2 Ae01 = SM01.hv * T01 + A01.hv;
            h2 Ae23 = SM23.hv * T23 + A23.hv;

            h2x2_h4 gg;
            gg.g2[0] = p01.hv * Ae01 + B01.hv;   // v_pk_fma_f16
            gg.g2[1] = p23.hv * Ae23 + B23.hv;

            // h += gelu(u) @ (V/N)  (residual add folded into MFMA C operand)
            h[t] = __builtin_amdgcn_mfma_f32_16x16x16f16(vf, gg.h4, h[t], 0, 0, 0);
        }

        wf = wfn; vf = vfn;
    }

    #pragma unroll
    for (int t = 0; t < 4; ++t) {
        float4 v = make_float4(h[t][0], h[t][1], h[t][2], h[t][3]);
        *reinterpret_cast<float4*>(out + (rowbase + t * 16 + r) * DDIM + 4 * q) = v;
    }
}

extern "C" void kernel_launch(void* const* d_in, const int* in_sizes, int n_in,
                              void* d_out, int out_size, void* d_ws, size_t ws_size,
                              hipStream_t stream) {
    const float* x = (const float*)d_in[0];   // [B, 16] fp32
    const float* W = (const float*)d_in[1];   // [64, 16, 16] fp32
    const float* V = (const float*)d_in[2];   // [64, 16, 16] fp32
    float* out = (float*)d_out;

    half4* pw = (half4*)d_ws;                 // 64 steps * 64 lanes * 8B = 32KB
    half4* pv = pw + NSTEPS * 64;             // +32KB
    unsigned* lut = (unsigned*)(pv + NSTEPS * 64); // +2KB (ws_size >= 66KB)

    pack_wv<<<16, 256, 0, stream>>>(W, V, pw, pv);
    build_lut_abs<<<2, 256, 0, stream>>>(lut);

    int batch = in_sizes[0] / DDIM;           // 2^21
    resnet_mfma_kernel<<<batch / 256, 256, 0, stream>>>(x, pw, pv, lut, out);
}

// Round 7
// 391.320 us; speedup vs baseline: 1.3949x; 1.3949x over previous
//
#include <hip/hip_runtime.h>
#include <math.h>

#define DDIM 16
#define NSTEPS 64
#define TILES 8            // row-tiles per wave (was 4): 2x independent chains

typedef __fp16   fp16x2  __attribute__((ext_vector_type(2)));
typedef _Float16 h2      __attribute__((ext_vector_type(2)));
typedef _Float16 half4   __attribute__((ext_vector_type(4)));
typedef float    floatx4 __attribute__((ext_vector_type(4)));

union pk_u      { fp16x2 fv; h2 hv; unsigned u; };
union h2x2_h4   { h2 g2[2]; half4 h4; };
union pk2_to_h4 { fp16x2 p2[2]; half4 h4; };
union us_h      { unsigned short u; _Float16 h; };

// ---------------------------------------------------------------------------
// Pre-pack W^T / V^T into per-lane MFMA A-operand fragments (f16).
// V fragments are pre-scaled by 1/NSTEPS.
// ---------------------------------------------------------------------------
__global__ __launch_bounds__(256) void pack_wv(const float* __restrict__ W,
                                               const float* __restrict__ V,
                                               half4* __restrict__ pw,
                                               half4* __restrict__ pv)
{
    int t = blockIdx.x * 256 + threadIdx.x;   // 0..4095 = 64 steps * 64 lanes
    int L = t & 63;
    int s = t >> 6;
    int q = L >> 4, r = L & 15;
    const float inv_n = 1.0f / (float)NSTEPS;
    const float* Ws = W + s * DDIM * DDIM;
    const float* Vs = V + s * DDIM * DDIM;
    half4 w, v;
    #pragma unroll
    for (int j = 0; j < 4; ++j) {
        w[j] = (_Float16)Ws[(4 * q + j) * DDIM + r];
        v[j] = (_Float16)(Vs[(4 * q + j) * DDIM + r] * inv_n);
    }
    pw[t] = w;
    pv[t] = v;
}

// ---------------------------------------------------------------------------
// GELU LUT indexed by the TOP 10 BITS of the f16 pattern of x (R4 version —
// best measured). 1024 log-spaced segments over the whole f16 domain, no
// clamping. Entry i: packed f16 (a,b), low16=a, gelu(x) ~= a*x + b.
// ---------------------------------------------------------------------------
__global__ __launch_bounds__(256) void build_lut16(unsigned* __restrict__ lut)
{
    int i = blockIdx.x * 256 + threadIdx.x;   // 0..1023
    int sign = i >> 9;
    int eo = (i >> 4) & 31;
    int en = ((i + 1) >> 4) & 31;
    float a, b;
    if (eo == 31 || en == 31) {               // segment touches inf/nan codes
        a = sign ? 0.0f : 1.0f;
        b = 0.0f;
    } else {
        us_h c0, c1;
        c0.u = (unsigned short)(i << 6);
        c1.u = (unsigned short)((i + 1) << 6);
        float x0 = (float)c0.h, x1 = (float)c1.h;
        float g0 = 0.5f * x0 * (1.0f + erff(x0 * 0.70710678f));
        float g1 = 0.5f * x1 * (1.0f + erff(x1 * 0.70710678f));
        a = (g1 - g0) / (x1 - x0);
        b = g0 - a * x0;
    }
    us_h ah, bh;
    ah.h = (_Float16)a;
    bh.h = (_Float16)b;
    lut[i] = ((unsigned)bh.u << 16) | (unsigned)ah.u;
}

// ---------------------------------------------------------------------------
// Main kernel: R4 GELU structure, but 8 row-tiles per wave (128 rows).
// 8 independent dependency chains per wave double the latency tolerance —
// R3/R5 showed the 4-chain version is latency-marginal (~190cy chain,
// ~26 chains/SIMD barely covers it; any added serial work regressed).
// ---------------------------------------------------------------------------
__global__ __launch_bounds__(256) void resnet_mfma_kernel(
    const float* __restrict__ x,
    const half4* __restrict__ pw,
    const half4* __restrict__ pv,
    const unsigned* __restrict__ lut_g,
    float* __restrict__ out)
{
    __shared__ unsigned lutw[1024];   // 4 KB

    const int tid  = threadIdx.x;
    const int lane = tid & 63;
    const int wave = tid >> 6;
    const int q = lane >> 4, r = lane & 15;

    // Stage LUT into LDS: 256 uint4 = 1024 u32, one per thread.
    {
        const uint4* src = reinterpret_cast<const uint4*>(lut_g);
        reinterpret_cast<uint4*>(lutw)[tid] = src[tid];
    }

    const long rowbase = (long)blockIdx.x * (256 / 64 * TILES * 16)
                       + (long)wave * (TILES * 16);

    floatx4 h[TILES];
    #pragma unroll
    for (int t = 0; t < TILES; ++t) {
        const float4* p = reinterpret_cast<const float4*>(
            x + (rowbase + t * 16 + r) * DDIM + 4 * q);
        float4 v = *p;
        h[t][0] = v.x; h[t][1] = v.y; h[t][2] = v.z; h[t][3] = v.w;
    }

    half4 wf = pw[lane];
    half4 vf = pv[lane];

    __syncthreads();   // LUT ready

    const char* lb = reinterpret_cast<const char*>(lutw);

    for (int s = 0; s < NSTEPS; ++s) {
        int sn = (s + 1) & (NSTEPS - 1);          // last iter wraps to 0 (unused)
        half4 wfn = pw[sn * 64 + lane];
        half4 vfn = pv[sn * 64 + lane];

        #pragma unroll
        for (int t = 0; t < TILES; ++t) {
            pk2_to_h4 hc;
            hc.p2[0] = __builtin_amdgcn_cvt_pkrtz(h[t][0], h[t][1]);
            hc.p2[1] = __builtin_amdgcn_cvt_pkrtz(h[t][2], h[t][3]);

            floatx4 zero = {0.f, 0.f, 0.f, 0.f};
            floatx4 u = __builtin_amdgcn_mfma_f32_16x16x16f16(wf, hc.h4, zero, 0, 0, 0);

            // u -> packed f16 (also the PWL input)
            pk_u p01, p23;
            p01.fv = __builtin_amdgcn_cvt_pkrtz(u[0], u[1]);
            p23.fv = __builtin_amdgcn_cvt_pkrtz(u[2], u[3]);

            // byte offsets = (f16 bits >> 6) * 4, straight from the packed words
            unsigned off0 = (p01.u >> 4) & 0xFFCu;
            unsigned off1 = (p01.u >> 20) & 0xFFCu;
            unsigned off2 = (p23.u >> 4) & 0xFFCu;
            unsigned off3 = (p23.u >> 20) & 0xFFCu;

            unsigned e0 = *reinterpret_cast<const unsigned*>(lb + off0);
            unsigned e1 = *reinterpret_cast<const unsigned*>(lb + off1);
            unsigned e2 = *reinterpret_cast<const unsigned*>(lb + off2);
            unsigned e3 = *reinterpret_cast<const unsigned*>(lb + off3);

            // repack (b|a)(b|a) -> (a1|a0), (b1|b0) ; then packed f16 fma
            pk_u a01, b01, a23, b23;
            a01.u = __builtin_amdgcn_perm(e1, e0, 0x05040100u);
            b01.u = __builtin_amdgcn_perm(e1, e0, 0x07060302u);
            a23.u = __builtin_amdgcn_perm(e3, e2, 0x05040100u);
            b23.u = __builtin_amdgcn_perm(e3, e2, 0x07060302u);

            h2x2_h4 gg;
            gg.g2[0] = a01.hv * p01.hv + b01.hv;   // v_pk_fma_f16
            gg.g2[1] = a23.hv * p23.hv + b23.hv;

            // h += gelu(u) @ (V/N)  (residual add folded into MFMA C operand)
            h[t] = __builtin_amdgcn_mfma_f32_16x16x16f16(vf, gg.h4, h[t], 0, 0, 0);
        }

        wf = wfn; vf = vfn;
    }

    #pragma unroll
    for (int t = 0; t < TILES; ++t) {
        float4 v = make_float4(h[t][0], h[t][1], h[t][2], h[t][3]);
        *reinterpret_cast<float4*>(out + (rowbase + t * 16 + r) * DDIM + 4 * q) = v;
    }
}

extern "C" void kernel_launch(void* const* d_in, const int* in_sizes, int n_in,
                              void* d_out, int out_size, void* d_ws, size_t ws_size,
                              hipStream_t stream) {
    const float* x = (const float*)d_in[0];   // [B, 16] fp32
    const float* W = (const float*)d_in[1];   // [64, 16, 16] fp32
    const float* V = (const float*)d_in[2];   // [64, 16, 16] fp32
    float* out = (float*)d_out;

    half4* pw = (half4*)d_ws;                 // 64 steps * 64 lanes * 8B = 32KB
    half4* pv = pw + NSTEPS * 64;             // +32KB
    unsigned* lut = (unsigned*)(pv + NSTEPS * 64); // +4KB (ws_size >= 68KB)

    pack_wv<<<16, 256, 0, stream>>>(W, V, pw, pv);
    build_lut16<<<4, 256, 0, stream>>>(lut);

    int batch = in_sizes[0] / DDIM;           // 2^21
    int rows_per_block = (256 / 64) * TILES * 16;   // 512
    resnet_mfma_kernel<<<batch / rows_per_block, 256, 0, stream>>>(x, pw, pv, lut, out);
}